// Round 1
// baseline (765.549 us; speedup 1.0000x reference)
//
#include <hip/hip_runtime.h>

#define BB 4
#define NN 1024
#define KK 100
#define TT 2
#define HH 64
#define FF 96

// d_out layout (floats): Etot [0,4) | Ei [4,4100) | Force [4100,16388) | Virial [16388,16424)
#define OFF_EI   4
#define OFF_F    (4 + BB*NN)
#define OFF_VIR  (4 + BB*NN + BB*NN*3)
#define OUT_TOT  (4 + BB*NN + BB*NN*3 + BB*9)

__device__ __forceinline__ float wave_sum(float v) {
    #pragma unroll
    for (int off = 32; off > 0; off >>= 1)
        v += __shfl_xor(v, off, 64);
    return v;
}

__global__ __launch_bounds__(256) void zero_kernel(float* __restrict__ out) {
    int i = blockIdx.x * blockDim.x + threadIdx.x;
    for (int idx = i; idx < OUT_TOT; idx += gridDim.x * blockDim.x)
        out[idx] = 0.f;
}

// One wave (64 threads) per (b,n) row. lane = hidden unit h.
__global__ __launch_bounds__(64) void mlp_kernel(
    const float* __restrict__ feat, const int* __restrict__ tmap,
    const float* __restrict__ W1, const float* __restrict__ b1,
    const float* __restrict__ W2, const float* __restrict__ b2,
    const float* __restrict__ rdt, const float* __restrict__ Wout,
    const float* __restrict__ bout,
    float* __restrict__ out, float* __restrict__ dE)
{
    const int row  = blockIdx.x;            // b*NN + n
    const int b    = row / NN;
    const int n    = row - b * NN;
    const int lane = threadIdx.x;
    const int t    = tmap[n];

    __shared__ float sfeat[FF];
    __shared__ float sh1[HH];
    __shared__ float sdz2[HH];
    __shared__ float sdz1[HH];

    const float* frow = feat + (size_t)row * FF;
    sfeat[lane] = frow[lane];
    if (lane < FF - HH) sfeat[HH + lane] = frow[HH + lane];
    __syncthreads();

    const float* W1t = W1 + (size_t)t * FF * HH;
    const float* W2t = W2 + (size_t)t * HH * HH;

    // forward
    float z1 = b1[t * HH + lane];
    #pragma unroll 8
    for (int f = 0; f < FF; ++f) z1 = fmaf(sfeat[f], W1t[f * HH + lane], z1);
    float h1 = tanhf(z1);
    sh1[lane] = h1;
    __syncthreads();

    float z2 = b2[t * HH + lane];
    #pragma unroll 8
    for (int h = 0; h < HH; ++h) z2 = fmaf(sh1[h], W2t[h * HH + lane], z2);
    float u  = tanhf(z2);
    float r  = rdt[t * HH + lane];
    float wo = Wout[t * HH + lane];
    float h2 = h1 + r * u;

    float e = wave_sum(h2 * wo);

    // backward (cotangent on Ei = 1)
    float dz2 = r * wo * (1.f - u * u);
    sdz2[lane] = dz2;
    __syncthreads();

    float dh1 = wo;
    #pragma unroll 8
    for (int g = 0; g < HH; ++g) dh1 = fmaf(sdz2[g], W2t[lane * HH + g], dh1);
    float dz1 = dh1 * (1.f - h1 * h1);
    sdz1[lane] = dz1;
    __syncthreads();

    float* dErow = dE + (size_t)row * FF;
    {
        float acc = 0.f;
        #pragma unroll 8
        for (int h = 0; h < HH; ++h) acc = fmaf(sdz1[h], W1t[lane * HH + h], acc);
        dErow[lane] = acc;
    }
    if (lane < FF - HH) {
        const int f = HH + lane;
        float acc = 0.f;
        #pragma unroll 8
        for (int h = 0; h < HH; ++h) acc = fmaf(sdz1[h], W1t[f * HH + h], acc);
        dErow[f] = acc;
    }

    if (lane == 0) {
        float Ei = e + bout[t];
        out[OFF_EI + row] = Ei;
        atomicAdd(&out[b], Ei);
    }
}

// One block (4 waves) per (b,n); wave w handles k = w, w+4, ...
__global__ __launch_bounds__(256) void pair_kernel(
    const float* __restrict__ dfeat, const float* __restrict__ ImageDR,
    const int* __restrict__ neigh, const float* __restrict__ dE,
    float* __restrict__ out)
{
    const int row  = blockIdx.x;            // b*NN + n
    const int b    = row / NN;
    const int tid  = threadIdx.x;
    const int wave = tid >> 6;
    const int lane = tid & 63;

    __shared__ float sdE[FF];
    __shared__ float swf[4][3];
    __shared__ float svir[4][9];

    if (tid < FF) sdE[tid] = dE[(size_t)row * FF + tid];
    __syncthreads();

    float sacc0 = 0.f, sacc1 = 0.f, sacc2 = 0.f;   // -sum_k pair_f (self force)
    float vacc  = 0.f;                             // per-lane virial entry (lanes 0..8)
    const int vx = lane / 3, vy = lane - 3 * (lane / 3);

    const float* drbase = ImageDR + (size_t)row * KK * 4;
    const int*   nb     = neigh   + (size_t)row * KK;

    for (int k = wave; k < KK; k += 4) {
        const float* dfp = dfeat + ((size_t)row * KK + k) * (FF * 3);
        float a0, a1, a2;
        {
            const int f = lane;
            const float w = sdE[f];
            a0 = dfp[f * 3 + 0] * w;
            a1 = dfp[f * 3 + 1] * w;
            a2 = dfp[f * 3 + 2] * w;
        }
        if (lane < FF - HH) {
            const int f = HH + lane;
            const float w = sdE[f];
            a0 = fmaf(dfp[f * 3 + 0], w, a0);
            a1 = fmaf(dfp[f * 3 + 1], w, a1);
            a2 = fmaf(dfp[f * 3 + 2], w, a2);
        }
        float pf0 = wave_sum(a0);
        float pf1 = wave_sum(a1);
        float pf2 = wave_sum(a2);

        const int j = nb[k];
        if (j <= 0) { pf0 = 0.f; pf1 = 0.f; pf2 = 0.f; }

        if (j > 0 && lane < 3) {
            const float v = (lane == 0) ? pf0 : ((lane == 1) ? pf1 : pf2);
            atomicAdd(&out[OFF_F + ((size_t)b * NN + (j - 1)) * 3 + lane], v);
        }

        sacc0 -= pf0; sacc1 -= pf1; sacc2 -= pf2;

        if (lane < 9) {
            const float rx  = drbase[k * 4 + 1 + vx];
            const float pfy = (vy == 0) ? pf0 : ((vy == 1) ? pf1 : pf2);
            vacc = fmaf(-rx, pfy, vacc);
        }
    }

    if (lane < 3) swf[wave][lane] = (lane == 0) ? sacc0 : ((lane == 1) ? sacc1 : sacc2);
    if (lane < 9) svir[wave][lane] = vacc;
    __syncthreads();

    if (tid < 3) {
        const float s = swf[0][tid] + swf[1][tid] + swf[2][tid] + swf[3][tid];
        atomicAdd(&out[OFF_F + (size_t)row * 3 + tid], s);
    }
    if (tid < 9) {
        const float s = svir[0][tid] + svir[1][tid] + svir[2][tid] + svir[3][tid];
        atomicAdd(&out[OFF_VIR + b * 9 + tid], s);
    }
}

extern "C" void kernel_launch(void* const* d_in, const int* in_sizes, int n_in,
                              void* d_out, int out_size, void* d_ws, size_t ws_size,
                              hipStream_t stream) {
    const float* feat    = (const float*)d_in[0];
    const float* dfeat   = (const float*)d_in[1];
    const float* ImageDR = (const float*)d_in[2];
    const int*   neigh   = (const int*)  d_in[3];
    const int*   tmap    = (const int*)  d_in[4];
    const float* W1      = (const float*)d_in[5];
    const float* b1      = (const float*)d_in[6];
    const float* W2      = (const float*)d_in[7];
    const float* b2      = (const float*)d_in[8];
    const float* rdt     = (const float*)d_in[9];
    const float* Wout    = (const float*)d_in[10];
    const float* bout    = (const float*)d_in[11];

    float* out = (float*)d_out;
    float* dE  = (float*)d_ws;   // B*N*FF floats = 1.5 MB

    zero_kernel<<<64, 256, 0, stream>>>(out);
    mlp_kernel<<<BB * NN, 64, 0, stream>>>(feat, tmap, W1, b1, W2, b2, rdt, Wout, bout, out, dE);
    pair_kernel<<<BB * NN, 256, 0, stream>>>(dfeat, ImageDR, neigh, dE, out);
}

// Round 2
// 741.621 us; speedup vs baseline: 1.0323x; 1.0323x over previous
//
#include <hip/hip_runtime.h>

#define BB 4
#define NN 1024
#define KK 100
#define HH 64
#define FF 96

// d_out layout (floats): Etot [0,4) | Ei [4,4100) | Force [4100,16388) | Virial [16388,16424)
#define OFF_EI   4
#define OFF_F    (4 + BB*NN)
#define OFF_VIR  (OFF_F + BB*NN*3)
#define OUT_TOT  (OFF_VIR + BB*9)

__device__ __forceinline__ float wave_sum(float v) {
    #pragma unroll
    for (int off = 32; off > 0; off >>= 1)
        v += __shfl_xor(v, off, 64);
    return v;
}

__global__ __launch_bounds__(256) void zero_kernel(float* __restrict__ out) {
    int i = blockIdx.x * 256 + threadIdx.x;
    if (i < OUT_TOT) out[i] = 0.f;
}

// One block (4 waves) per (b,n) row.
// Wave 0: full MLP fwd + VJP in registers (shuffle broadcasts, no barriers),
// writes dE[96] to LDS. Then all 4 waves contract dE against dfeat over k.
__global__ __launch_bounds__(256) void fused_kernel(
    const float* __restrict__ feat, const int* __restrict__ tmap,
    const float* __restrict__ W1, const float* __restrict__ b1,
    const float* __restrict__ W2, const float* __restrict__ b2,
    const float* __restrict__ rdt, const float* __restrict__ Wout,
    const float* __restrict__ bout,
    const float* __restrict__ dfeat, const float* __restrict__ ImageDR,
    const int* __restrict__ neigh, float* __restrict__ out)
{
    const int row  = blockIdx.x;            // b*NN + n
    const int b    = row / NN;
    const int n    = row - b * NN;
    const int tid  = threadIdx.x;
    const int wave = tid >> 6;
    const int lane = tid & 63;

    __shared__ float sdE[FF];
    __shared__ float sdr[KK * 4];
    __shared__ int   snb[KK];
    __shared__ float swf[4][3];
    __shared__ float svir[4][9];

    // cooperative preloads (coalesced)
    const float* drbase = ImageDR + (size_t)row * (KK * 4);
    for (int i = tid; i < KK * 4; i += 256) sdr[i] = drbase[i];
    if (tid < KK) snb[tid] = neigh[(size_t)row * KK + tid];

    if (wave == 0) {
        const int t = tmap[n];
        const float* frow = feat + (size_t)row * FF;
        const float* W1t  = W1 + (size_t)t * FF * HH;
        const float* W2t  = W2 + (size_t)t * HH * HH;

        float f0 = frow[lane];                                 // f = lane
        float f1 = (lane < 32) ? frow[HH + lane] : 0.f;        // f = 64+lane

        // forward: z1 = feat·W1 + b1   (lane = hidden unit)
        float z1 = b1[t * HH + lane];
        #pragma unroll 8
        for (int f = 0; f < HH; ++f)
            z1 = fmaf(__shfl(f0, f, 64), W1t[f * HH + lane], z1);
        #pragma unroll 8
        for (int f = 0; f < FF - HH; ++f)
            z1 = fmaf(__shfl(f1, f, 64), W1t[(HH + f) * HH + lane], z1);
        float h1 = tanhf(z1);

        float z2 = b2[t * HH + lane];
        #pragma unroll 8
        for (int h = 0; h < HH; ++h)
            z2 = fmaf(__shfl(h1, h, 64), W2t[h * HH + lane], z2);
        float u  = tanhf(z2);
        float r  = rdt[t * HH + lane];
        float wo = Wout[t * HH + lane];

        float e = wave_sum((h1 + r * u) * wo);

        // backward (cotangent 1 on Ei)
        float dz2 = r * wo * (1.f - u * u);
        float dh1 = wo;
        #pragma unroll 8
        for (int g = 0; g < HH; ++g)
            dh1 = fmaf(__shfl(dz2, g, 64), W2t[lane * HH + g], dh1);
        float dz1 = dh1 * (1.f - h1 * h1);

        float acc0 = 0.f, acc1 = 0.f;
        #pragma unroll 8
        for (int h = 0; h < HH; ++h) {
            const float d = __shfl(dz1, h, 64);
            acc0 = fmaf(d, W1t[lane * HH + h], acc0);
            if (lane < 32) acc1 = fmaf(d, W1t[(HH + lane) * HH + h], acc1);
        }
        sdE[lane] = acc0;
        if (lane < 32) sdE[HH + lane] = acc1;

        if (lane == 0) {
            const float Ei = e + bout[t];
            out[OFF_EI + row] = Ei;
            atomicAdd(&out[b], Ei);
        }
    }
    __syncthreads();

    const float w0 = sdE[lane];
    const float w1 = (lane < 32) ? sdE[HH + lane] : 0.f;

    float sacc0 = 0.f, sacc1 = 0.f, sacc2 = 0.f;   // -sum_k pair_f (self force)
    float vacc  = 0.f;                             // virial entry (lanes 0..8)
    const int vx = lane / 3, vy = lane - 3 * vx;

    const size_t pbase = (size_t)row * KK;

    #pragma unroll 2
    for (int k = wave; k < KK; k += 4) {
        const float* dfp = dfeat + (pbase + k) * (FF * 3);
        float a0 = dfp[lane * 3 + 0] * w0;
        float a1 = dfp[lane * 3 + 1] * w0;
        float a2 = dfp[lane * 3 + 2] * w0;
        if (lane < 32) {
            const int m = (HH + lane) * 3;
            a0 = fmaf(dfp[m + 0], w1, a0);
            a1 = fmaf(dfp[m + 1], w1, a1);
            a2 = fmaf(dfp[m + 2], w1, a2);
        }
        float pf0 = wave_sum(a0);
        float pf1 = wave_sum(a1);
        float pf2 = wave_sum(a2);

        const int j = snb[k];
        if (j <= 0) { pf0 = 0.f; pf1 = 0.f; pf2 = 0.f; }
        else if (lane < 3) {
            const float v = (lane == 0) ? pf0 : ((lane == 1) ? pf1 : pf2);
            atomicAdd(&out[OFF_F + ((size_t)b * NN + (j - 1)) * 3 + lane], v);
        }

        sacc0 -= pf0; sacc1 -= pf1; sacc2 -= pf2;

        if (lane < 9) {
            const float rx  = sdr[k * 4 + 1 + vx];
            const float pfy = (vy == 0) ? pf0 : ((vy == 1) ? pf1 : pf2);
            vacc = fmaf(-rx, pfy, vacc);
        }
    }

    if (lane < 3) swf[wave][lane]  = (lane == 0) ? sacc0 : ((lane == 1) ? sacc1 : sacc2);
    if (lane < 9) svir[wave][lane] = vacc;
    __syncthreads();

    if (tid < 3) atomicAdd(&out[OFF_F + (size_t)row * 3 + tid],
                           swf[0][tid] + swf[1][tid] + swf[2][tid] + swf[3][tid]);
    if (tid < 9) atomicAdd(&out[OFF_VIR + b * 9 + tid],
                           svir[0][tid] + svir[1][tid] + svir[2][tid] + svir[3][tid]);
}

extern "C" void kernel_launch(void* const* d_in, const int* in_sizes, int n_in,
                              void* d_out, int out_size, void* d_ws, size_t ws_size,
                              hipStream_t stream) {
    const float* feat    = (const float*)d_in[0];
    const float* dfeat   = (const float*)d_in[1];
    const float* ImageDR = (const float*)d_in[2];
    const int*   neigh   = (const int*)  d_in[3];
    const int*   tmap    = (const int*)  d_in[4];
    const float* W1      = (const float*)d_in[5];
    const float* b1      = (const float*)d_in[6];
    const float* W2      = (const float*)d_in[7];
    const float* b2      = (const float*)d_in[8];
    const float* rdt     = (const float*)d_in[9];
    const float* Wout    = (const float*)d_in[10];
    const float* bout    = (const float*)d_in[11];

    float* out = (float*)d_out;

    zero_kernel<<<(OUT_TOT + 255) / 256, 256, 0, stream>>>(out);
    fused_kernel<<<BB * NN, 256, 0, stream>>>(feat, tmap, W1, b1, W2, b2, rdt,
                                              Wout, bout, dfeat, ImageDR, neigh, out);
}